// Round 2
// baseline (23241.463 us; speedup 1.0000x reference)
//
#include <hip/hip_runtime.h>
#include <math.h>

// Persistent-kernel LSTM: H=2048, SEQ=4096, fp32 (no fp32 MFMA -> vector ALU).
// 256 WGs x 512 thr, 1 WG/CU. Wave w of WG g owns hidden unit k=g*8+w; each
// lane holds 4 gate-rows x 32 cols of W_hh (128 floats, AGPR-backed).
//
// Cross-step exchange v4: SCOUT-GATHERS-DATA (sentinel ring, no flags,
// 1 barrier/step, centralized detection).
//   ring[NS=4][2048] floats in d_ws. |h| < 1 strictly -> qNaN bits
//   0x7fc00000 is an unreachable sentinel. Producers store h directly
//   (relaxed agent -> LLC) -- no flag, no drain-then-flag trip.
//   Wave 0 ("scout") polls slot (t-1)&3: 32 coalesced values per lane
//   (lane + 64*j), re-loading ONLY still-sentinel values each sweep.
//   On success the scout already holds all 2048 h values in registers ->
//   writes them to LDS -> one barrier -> everyone computes. The poll IS
//   the data load; the separate post-flag load trip of v2 is gone.
//   v3 post-mortem: per-thread decentralized polling made the step time a
//   max over 512 independent detection chains (latency, not bandwidth, was
//   the regression: VALU-time FELL while dur doubled). Centralized scout +
//   barrier restores v2's per-step re-synchronization.
// Slot lifecycle: produced at t, consumed (gathered) at t+1, sentinel-reset
//   at t+2. Safety: our gather success at step t proves every WG published
//   h_{t-1}, hence finished its step-(t-1) gather of slot (t-2)&3 -> that
//   slot is reset-safe at step t. Reset stores drain at the resetter's next
//   __syncthreads (vmcnt 0) before it can publish again -> per-location
//   coherence guarantees no stale pre-reset value is ever re-observed.
// d_ws usage: 32 KB.

#define HDIM 2048
#define SEQ 4096
#define NWG 256
#define TPB 512
#define NS 4                    // ring slots (power of 2, >= 3 for slack)
#define SENTB 0x7fc00000u       // qNaN bits: impossible for |h|<1
#define GUARD_MAX 65536         // protocol-failure escape (no hang; NaNs -> loud fail)

__device__ __forceinline__ float sigmoidf_(float x) {
  return __builtin_amdgcn_rcpf(1.0f + __expf(-x));
}
__device__ __forceinline__ float tanh_(float x) {
  float e = __expf(-2.0f * fabsf(x));
  float r = (1.0f - e) * __builtin_amdgcn_rcpf(1.0f + e);
  return copysignf(r, x);
}

// slots 0..NS-2 <- sentinel; slot NS-1 <- 0.0f (h_{-1} = 0, gathered at t=0)
__global__ void lstm_init(unsigned* ring) {
  const int i = blockIdx.x * 256 + threadIdx.x;   // 32 blocks x 256 = 8192
  ring[i] = (i < (NS - 1) * HDIM) ? SENTB : 0u;
}

__global__ __launch_bounds__(TPB, 2) void lstm_persist(
    const float* __restrict__ x, const float* __restrict__ w_ih,
    const float* __restrict__ w_hh, const float* __restrict__ b_ih,
    const float* __restrict__ b_hh, const float* __restrict__ w_out,
    const float* __restrict__ b_out, float* __restrict__ out,
    unsigned* __restrict__ ring)
{
  const int wg   = blockIdx.x;
  const int tid  = threadIdx.x;
  const int wave = tid >> 6;
  const int lane = tid & 63;
  const int k    = wg * 8 + wave;   // this wave's hidden unit

  __shared__ float xs[SEQ];        // 16 KB
  __shared__ float hs[2][HDIM];    // 16 KB, double-buffered by parity
  __shared__ float wys[2][8];      // per-wave y partials, double-buffered

  // ---- one-time: weights into registers ----
  // rows g=0..3 (gates i,f,g,o of unit k): row = k + g*HDIM
  // cols per lane: {256*j + 4*lane + q}, j=0..7, q=0..3  -> 32 float4
  float4 W[32];
  float wx[4], bb[4];
  #pragma unroll
  for (int g = 0; g < 4; ++g) {
    const int row = k + g * HDIM;
    const float* rp = w_hh + (size_t)row * HDIM + lane * 4;
    #pragma unroll
    for (int j = 0; j < 8; ++j)
      W[g * 8 + j] = *(const float4*)(rp + j * 256);
    wx[g] = w_ih[row];
    bb[g] = b_ih[row] + b_hh[row];
  }
  float wo[4];
  #pragma unroll
  for (int q = 0; q < 4; ++q) wo[q] = w_out[tid + TPB * q];
  const float bout = b_out[0];

  for (int i = tid; i < SEQ; i += TPB) xs[i] = x[i];

  float cc = 0.f, hh = 0.f;

  for (int t = 0; t < SEQ; ++t) {
    const int par = t & 1;

    // ---- scout: wave 0 gathers slot (t-1)&3 (poll IS the load) ----
    if (wave == 0) {
      const unsigned* base =
          ring + (size_t)((t + NS - 1) & (NS - 1)) * HDIM + lane;
      unsigned v[32];
      #pragma unroll
      for (int j = 0; j < 32; ++j)
        v[j] = __hip_atomic_load(base + 64 * j, __ATOMIC_RELAXED,
                                 __HIP_MEMORY_SCOPE_AGENT);
      for (int guard = 0;;) {
        int miss = 0;
        #pragma unroll
        for (int j = 0; j < 32; ++j) miss |= (v[j] == SENTB);
        if (!__any(miss) || ++guard > GUARD_MAX) break;
        #pragma unroll
        for (int j = 0; j < 32; ++j)      // selective re-load: only missing
          if (v[j] == SENTB)
            v[j] = __hip_atomic_load(base + 64 * j, __ATOMIC_RELAXED,
                                     __HIP_MEMORY_SCOPE_AGENT);
      }
      // distribute h_{t-1} to LDS (lane+64j: consecutive lanes consecutive
      // addrs -> conflict-free b32 writes)
      #pragma unroll
      for (int j = 0; j < 32; ++j)
        hs[par][lane + 64 * j] = __uint_as_float(v[j]);
    }
    __syncthreads();  // B1: hs[par] ready; also drains last step's stores

    // ---- off-path: sentinel-reset slot (t-2)&3 for its next epoch ----
    if (t >= 1 && lane == 0)
      __hip_atomic_store(ring + (size_t)((t + 2) & (NS - 1)) * HDIM + k,
                         SENTB, __ATOMIC_RELAXED, __HIP_MEMORY_SCOPE_AGENT);

    // ---- off-path: drain y_{t-2} (wys[par^1] written at step t-1) ----
    if (t >= 2 && wg == 0 && tid == 0)
      out[t - 2] = wys[par ^ 1][0] + wys[par ^ 1][1] + wys[par ^ 1][2] +
                   wys[par ^ 1][3] + wys[par ^ 1][4] + wys[par ^ 1][5] +
                   wys[par ^ 1][6] + wys[par ^ 1][7] + bout;

    // ---- z = W_hh @ h (per-lane partials over 32 columns) ----
    float acc[4] = {0.f, 0.f, 0.f, 0.f};
    #pragma unroll
    for (int j = 0; j < 8; ++j) {
      const float4 h4 = *(const float4*)&hs[par][j * 256 + lane * 4];
      #pragma unroll
      for (int g = 0; g < 4; ++g) {
        const float4 w = W[g * 8 + j];
        acc[g] = fmaf(w.x, h4.x, acc[g]);
        acc[g] = fmaf(w.y, h4.y, acc[g]);
        acc[g] = fmaf(w.z, h4.z, acc[g]);
        acc[g] = fmaf(w.w, h4.w, acc[g]);
      }
    }
    // ---- 16-shuffle reduction: fold xor32, pack gate pairs into halves,
    // 5 within-half stages, 1 cross-half gather (verified in prior round) ----
    const float a0 = acc[0] + __shfl_xor(acc[0], 32, 64);
    const float a1 = acc[1] + __shfl_xor(acc[1], 32, 64);
    const float a2 = acc[2] + __shfl_xor(acc[2], 32, 64);
    const float a3 = acc[3] + __shfl_xor(acc[3], 32, 64);
    const bool lohalf = (lane < 32);
    float s01 = lohalf ? a0 : a1;
    float s23 = lohalf ? a2 : a3;
    #pragma unroll
    for (int off = 16; off >= 1; off >>= 1) {
      s01 += __shfl_xor(s01, off, 64);
      s23 += __shfl_xor(s23, off, 64);
    }
    const float o01 = __shfl_xor(s01, 32, 64);
    const float o23 = __shfl_xor(s23, 32, 64);
    float z[4];
    z[0] = lohalf ? s01 : o01;
    z[1] = lohalf ? o01 : s01;
    z[2] = lohalf ? s23 : o23;
    z[3] = lohalf ? o23 : s23;

    const float xt = xs[t];
    #pragma unroll
    for (int g = 0; g < 4; ++g) z[g] = fmaf(xt, wx[g], z[g] + bb[g]);

    // ---- gates (lane-redundant, identical values) ----
    const float gi = sigmoidf_(z[0]), gf = sigmoidf_(z[1]);
    const float gg = tanh_(z[2]), go = sigmoidf_(z[3]);
    cc = gf * cc + gi * gg;
    hh = go * tanh_(cc);

    // ---- publish h_t: data IS the flag (drains at our next B1 at latest) ----
    if (lane == 0)
      __hip_atomic_store(ring + (size_t)(t & (NS - 1)) * HDIM + k,
                         __float_as_uint(hh), __ATOMIC_RELAXED,
                         __HIP_MEMORY_SCOPE_AGENT);

    // ---- off-path: y_{t-1} partial from hs[par] ----
    float sy = 0.f;
    #pragma unroll
    for (int q = 0; q < 4; ++q) sy = fmaf(wo[q], hs[par][tid + TPB * q], sy);
    #pragma unroll
    for (int off = 32; off >= 1; off >>= 1) sy += __shfl_xor(sy, off, 64);
    if (lane == 0) wys[par][wave] = sy;
  }

  // ---- epilogue ----
  // final h, c
  if (lane == 0) {
    out[SEQ + k] = hh;
    out[SEQ + HDIM + k] = cc;
  }

  __syncthreads();  // wys[1] (y partial for h_{SEQ-2}) complete
  if (wg == 0) {
    if (tid == 0)
      out[SEQ - 2] = wys[1][0] + wys[1][1] + wys[1][2] + wys[1][3] +
                     wys[1][4] + wys[1][5] + wys[1][6] + wys[1][7] + bout;

    // gather h_{SEQ-1} (slot (SEQ-1)&3 == 3) into hs[0], then y_{SEQ-1}
    if (wave == 0) {
      const unsigned* base = ring + (size_t)((SEQ - 1) & (NS - 1)) * HDIM + lane;
      unsigned v[32];
      #pragma unroll
      for (int j = 0; j < 32; ++j)
        v[j] = __hip_atomic_load(base + 64 * j, __ATOMIC_RELAXED,
                                 __HIP_MEMORY_SCOPE_AGENT);
      for (int guard = 0;;) {
        int miss = 0;
        #pragma unroll
        for (int j = 0; j < 32; ++j) miss |= (v[j] == SENTB);
        if (!__any(miss) || ++guard > GUARD_MAX) break;
        #pragma unroll
        for (int j = 0; j < 32; ++j)
          if (v[j] == SENTB)
            v[j] = __hip_atomic_load(base + 64 * j, __ATOMIC_RELAXED,
                                     __HIP_MEMORY_SCOPE_AGENT);
      }
      #pragma unroll
      for (int j = 0; j < 32; ++j)
        hs[0][lane + 64 * j] = __uint_as_float(v[j]);
    }
    __syncthreads();
    float sy = 0.f;
    #pragma unroll
    for (int q = 0; q < 4; ++q) sy = fmaf(wo[q], hs[0][tid + TPB * q], sy);
    #pragma unroll
    for (int off = 32; off >= 1; off >>= 1) sy += __shfl_xor(sy, off, 64);
    if (lane == 0) wys[0][wave] = sy;
    __syncthreads();
    if (tid == 0)
      out[SEQ - 1] = wys[0][0] + wys[0][1] + wys[0][2] + wys[0][3] +
                     wys[0][4] + wys[0][5] + wys[0][6] + wys[0][7] + bout;
  }
}

extern "C" void kernel_launch(void* const* d_in, const int* in_sizes, int n_in,
                              void* d_out, int out_size, void* d_ws, size_t ws_size,
                              hipStream_t stream) {
  const float* x     = (const float*)d_in[0];
  const float* w_ih  = (const float*)d_in[1];
  const float* w_hh  = (const float*)d_in[2];
  const float* b_ih  = (const float*)d_in[3];
  const float* b_hh  = (const float*)d_in[4];
  const float* w_out = (const float*)d_in[5];
  const float* b_out = (const float*)d_in[6];
  float* out = (float*)d_out;

  // ws layout: [0, 32KB): ring[4][2048] float (sentinel-coded h slots)
  unsigned* ring = (unsigned*)d_ws;

  lstm_init<<<32, 256, 0, stream>>>(ring);
  lstm_persist<<<NWG, TPB, 0, stream>>>(x, w_ih, w_hh, b_ih, b_hh, w_out,
                                        b_out, out, ring);
}

// Round 3
// 10991.190 us; speedup vs baseline: 2.1146x; 2.1146x over previous
//
#include <hip/hip_runtime.h>
#include <math.h>

// Persistent-kernel LSTM: H=2048, SEQ=4096, fp32 (no fp32 MFMA -> vector ALU).
// 256 WGs x 512 thr, 1 WG/CU. Wave w of WG g owns hidden unit k=g*8+w; each
// lane holds 4 gate-rows x 32 cols of W_hh (128 floats).
//
// Cross-step exchange: v2 FLAG PROTOCOL (proven 11.95ms) -- reinstated after
// v3/v4 post-mortem showed that polling data lines that are concurrently
// being written (sentinel schemes) delays store visibility at the LLC
// (~2x regression both times). Rule: poll small dedicated flag lines only;
// touch data exactly once after confirmation.
//   data:  float hval[2][2048]  (relaxed agent stores, -> LLC)
//   ready: uint  flags[2][256]  (per-WG flag = t+1, stored by tid0 AFTER
//          __syncthreads drains all waves' data stores to the LLC)
//   consumer: wave 0 only polls all 256 flags -- v5: PIPELINED double-buffer
//          sweeps (a sweep always in flight -> detect granularity ~ half an
//          LLC round trip), then one barrier, then each thread loads its 4
//          h values ONCE.
// v5 on-path trims vs v2: __expf/rcp gates (4 transcendentals on the serial
// path), 16-shuffle reduction instead of 24 (both numerically verified in
// v3/v4 rounds, absmax 3e-08).
// y is computed off-path from the already-loaded hv and drained with a
// 2-step delay by WG0. d_ws usage: 18 KB.

#define HDIM 2048
#define SEQ 4096
#define NWG 256
#define TPB 512
#define GUARD_MAX 4096   // protocol-failure escape (no hang)

__device__ __forceinline__ float sigmoidf_(float x) {
  return __builtin_amdgcn_rcpf(1.0f + __expf(-x));
}
__device__ __forceinline__ float tanh_(float x) {
  float e = __expf(-2.0f * fabsf(x));
  float r = (1.0f - e) * __builtin_amdgcn_rcpf(1.0f + e);
  return copysignf(r, x);
}

// zero slot-1 values (h_{-1}=0, consumed at t=0) and ALL flags
__global__ void lstm_init(float* hval, unsigned* flags) {
  const int i = blockIdx.x * 256 + threadIdx.x;   // 8 blocks x 256 = 2048
  hval[HDIM + i] = 0.f;
  if (i < 2 * NWG) flags[i] = 0u;
}

__global__ __launch_bounds__(TPB, 2) void lstm_persist(
    const float* __restrict__ x, const float* __restrict__ w_ih,
    const float* __restrict__ w_hh, const float* __restrict__ b_ih,
    const float* __restrict__ b_hh, const float* __restrict__ w_out,
    const float* __restrict__ b_out, float* __restrict__ out,
    float* __restrict__ hval, unsigned* __restrict__ flags)
{
  const int wg   = blockIdx.x;
  const int tid  = threadIdx.x;
  const int wave = tid >> 6;
  const int lane = tid & 63;
  const int k    = wg * 8 + wave;   // this wave's hidden unit

  __shared__ float xs[SEQ];        // 16 KB
  __shared__ float hs[2][HDIM];    // 16 KB, double-buffered
  __shared__ float wys[2][8];      // per-wave y partials, double-buffered

  // ---- one-time: weights into registers ----
  // rows g=0..3 (gates i,f,g,o of unit k): row = k + g*HDIM
  // cols per lane: {256*j + 4*lane + q}, j=0..7, q=0..3  -> 32 float4
  float4 W[32];
  float wx[4], bb[4];
  #pragma unroll
  for (int g = 0; g < 4; ++g) {
    const int row = k + g * HDIM;
    const float* rp = w_hh + (size_t)row * HDIM + lane * 4;
    #pragma unroll
    for (int j = 0; j < 8; ++j)
      W[g * 8 + j] = *(const float4*)(rp + j * 256);
    wx[g] = w_ih[row];
    bb[g] = b_ih[row] + b_hh[row];
  }
  float wo[4];
  #pragma unroll
  for (int q = 0; q < 4; ++q) wo[q] = w_out[tid + TPB * q];
  const float bout = b_out[0];

  for (int i = tid; i < SEQ; i += TPB) xs[i] = x[i];

  float cc = 0.f, hh = 0.f;
  float hv[4];
  __syncthreads();

  for (int t = 0; t < SEQ; ++t) {
    const int par = t & 1;

    // ---- scout: wave 0 polls all 256 flags of slot par^1 for value t ----
    // v5: double-buffered sweeps -- one sweep always in flight, so detect
    // granularity ~ half an LLC round trip instead of a full one.
    if (wave == 0) {
      const unsigned* f = flags + (par ^ 1) * NWG;
      const unsigned tv = (unsigned)t;
      unsigned a0, a1, a2, a3, c0, c1, c2, c3;
      a0 = __hip_atomic_load(&f[lane], __ATOMIC_RELAXED,
                             __HIP_MEMORY_SCOPE_AGENT);
      a1 = __hip_atomic_load(&f[lane + 64], __ATOMIC_RELAXED,
                             __HIP_MEMORY_SCOPE_AGENT);
      a2 = __hip_atomic_load(&f[lane + 128], __ATOMIC_RELAXED,
                             __HIP_MEMORY_SCOPE_AGENT);
      a3 = __hip_atomic_load(&f[lane + 192], __ATOMIC_RELAXED,
                             __HIP_MEMORY_SCOPE_AGENT);
      int guard = 0;
      for (;;) {
        // issue sweep B before checking sweep A
        c0 = __hip_atomic_load(&f[lane], __ATOMIC_RELAXED,
                               __HIP_MEMORY_SCOPE_AGENT);
        c1 = __hip_atomic_load(&f[lane + 64], __ATOMIC_RELAXED,
                               __HIP_MEMORY_SCOPE_AGENT);
        c2 = __hip_atomic_load(&f[lane + 128], __ATOMIC_RELAXED,
                               __HIP_MEMORY_SCOPE_AGENT);
        c3 = __hip_atomic_load(&f[lane + 192], __ATOMIC_RELAXED,
                               __HIP_MEMORY_SCOPE_AGENT);
        if (__all((a0 == tv) & (a1 == tv) & (a2 == tv) & (a3 == tv))) break;
        if (++guard > GUARD_MAX) break;
        // issue sweep A before checking sweep B
        a0 = __hip_atomic_load(&f[lane], __ATOMIC_RELAXED,
                               __HIP_MEMORY_SCOPE_AGENT);
        a1 = __hip_atomic_load(&f[lane + 64], __ATOMIC_RELAXED,
                               __HIP_MEMORY_SCOPE_AGENT);
        a2 = __hip_atomic_load(&f[lane + 128], __ATOMIC_RELAXED,
                               __HIP_MEMORY_SCOPE_AGENT);
        a3 = __hip_atomic_load(&f[lane + 192], __ATOMIC_RELAXED,
                               __HIP_MEMORY_SCOPE_AGENT);
        if (__all((c0 == tv) & (c1 == tv) & (c2 == tv) & (c3 == tv))) break;
        if (++guard > GUARD_MAX) break;
      }
    }
    __syncthreads();  // B1: h_{t-1} fully published at the LLC

    // ---- load h_{t-1} ONCE (agent -> LLC), stage to LDS ----
    const float* hsrc = hval + (par ^ 1) * HDIM;
    #pragma unroll
    for (int q = 0; q < 4; ++q)
      hv[q] = __hip_atomic_load(&hsrc[tid + TPB * q], __ATOMIC_RELAXED,
                                __HIP_MEMORY_SCOPE_AGENT);
    #pragma unroll
    for (int q = 0; q < 4; ++q) hs[par][tid + TPB * q] = hv[q];
    __syncthreads();  // B2: hs ready (also: wys[par^1] stable to read)

    // ---- drain y_{t-2} (wys[par^1] written at step t-1) ----
    if (t >= 2 && wg == 0 && tid == 0)
      out[t - 2] = wys[par ^ 1][0] + wys[par ^ 1][1] + wys[par ^ 1][2] +
                   wys[par ^ 1][3] + wys[par ^ 1][4] + wys[par ^ 1][5] +
                   wys[par ^ 1][6] + wys[par ^ 1][7] + bout;

    // ---- z = W_hh @ h (per-lane partials over 32 columns) ----
    float acc[4] = {0.f, 0.f, 0.f, 0.f};
    #pragma unroll
    for (int j = 0; j < 8; ++j) {
      const float4 h4 = *(const float4*)&hs[par][j * 256 + lane * 4];
      #pragma unroll
      for (int g = 0; g < 4; ++g) {
        const float4 w = W[g * 8 + j];
        acc[g] = fmaf(w.x, h4.x, acc[g]);
        acc[g] = fmaf(w.y, h4.y, acc[g]);
        acc[g] = fmaf(w.z, h4.z, acc[g]);
        acc[g] = fmaf(w.w, h4.w, acc[g]);
      }
    }
    // ---- 16-shuffle reduction: fold xor32, pack gate pairs into halves,
    // 5 within-half stages, 1 cross-half gather (verified prior rounds) ----
    const float a0 = acc[0] + __shfl_xor(acc[0], 32, 64);
    const float a1 = acc[1] + __shfl_xor(acc[1], 32, 64);
    const float a2 = acc[2] + __shfl_xor(acc[2], 32, 64);
    const float a3 = acc[3] + __shfl_xor(acc[3], 32, 64);
    const bool lohalf = (lane < 32);
    float s01 = lohalf ? a0 : a1;
    float s23 = lohalf ? a2 : a3;
    #pragma unroll
    for (int off = 16; off >= 1; off >>= 1) {
      s01 += __shfl_xor(s01, off, 64);
      s23 += __shfl_xor(s23, off, 64);
    }
    const float o01 = __shfl_xor(s01, 32, 64);
    const float o23 = __shfl_xor(s23, 32, 64);
    float z[4];
    z[0] = lohalf ? s01 : o01;
    z[1] = lohalf ? o01 : s01;
    z[2] = lohalf ? s23 : o23;
    z[3] = lohalf ? o23 : s23;

    const float xt = xs[t];
    #pragma unroll
    for (int g = 0; g < 4; ++g) z[g] = fmaf(xt, wx[g], z[g] + bb[g]);

    // ---- gates (lane-redundant, identical values) ----
    const float gi = sigmoidf_(z[0]), gf = sigmoidf_(z[1]);
    const float gg = tanh_(z[2]), go = sigmoidf_(z[3]);
    cc = gf * cc + gi * gg;
    hh = go * tanh_(cc);

    // ---- publish h_t ----
    if (lane == 0)
      __hip_atomic_store(&hval[par * HDIM + k], hh, __ATOMIC_RELAXED,
                         __HIP_MEMORY_SCOPE_AGENT);
    __syncthreads();  // B3: drains ALL waves' data stores (vmcnt(0) -> LLC)
    if (tid == 0)
      __hip_atomic_store(&flags[par * NWG + wg], (unsigned)(t + 1),
                         __ATOMIC_RELAXED, __HIP_MEMORY_SCOPE_AGENT);

    // ---- off-path: y_{t-1} partial from hv (h_{t-1}) ----
    float sy = 0.f;
    #pragma unroll
    for (int q = 0; q < 4; ++q) sy = fmaf(wo[q], hv[q], sy);
    #pragma unroll
    for (int off = 32; off >= 1; off >>= 1) sy += __shfl_xor(sy, off, 64);
    if (lane == 0) wys[par][wave] = sy;
  }

  // ---- epilogue ----
  __syncthreads();  // wys[1] (y partial for h_{SEQ-2}) complete
  if (wg == 0 && tid == 0)
    out[SEQ - 2] = wys[1][0] + wys[1][1] + wys[1][2] + wys[1][3] + wys[1][4] +
                   wys[1][5] + wys[1][6] + wys[1][7] + bout;

  if (wg == 0) {
    // poll flags slot1 == SEQ, then y_{SEQ-1} = w_out . h_{SEQ-1}
    if (wave == 0) {
      const unsigned* f = flags + NWG;  // slot (SEQ-1)&1 = 1
      int guard = 0;
      for (;;) {
        const unsigned f0 = __hip_atomic_load(&f[lane], __ATOMIC_RELAXED,
                                              __HIP_MEMORY_SCOPE_AGENT);
        const unsigned f1 = __hip_atomic_load(&f[lane + 64], __ATOMIC_RELAXED,
                                              __HIP_MEMORY_SCOPE_AGENT);
        const unsigned f2 = __hip_atomic_load(&f[lane + 128], __ATOMIC_RELAXED,
                                              __HIP_MEMORY_SCOPE_AGENT);
        const unsigned f3 = __hip_atomic_load(&f[lane + 192], __ATOMIC_RELAXED,
                                              __HIP_MEMORY_SCOPE_AGENT);
        const int ok = (f0 == (unsigned)SEQ) & (f1 == (unsigned)SEQ) &
                       (f2 == (unsigned)SEQ) & (f3 == (unsigned)SEQ);
        if (__all(ok)) break;
        if (++guard > GUARD_MAX) break;
      }
    }
    __syncthreads();
    float sy = 0.f;
    #pragma unroll
    for (int q = 0; q < 4; ++q) {
      const float hq = __hip_atomic_load(&hval[HDIM + tid + TPB * q],
                                         __ATOMIC_RELAXED,
                                         __HIP_MEMORY_SCOPE_AGENT);
      sy = fmaf(wo[q], hq, sy);
    }
    #pragma unroll
    for (int off = 32; off >= 1; off >>= 1) sy += __shfl_xor(sy, off, 64);
    if (lane == 0) wys[0][wave] = sy;
    __syncthreads();
    if (tid == 0)
      out[SEQ - 1] = wys[0][0] + wys[0][1] + wys[0][2] + wys[0][3] +
                     wys[0][4] + wys[0][5] + wys[0][6] + wys[0][7] + bout;
  }

  // ---- final h, c ----
  if (lane == 0) {
    out[SEQ + k] = hh;
    out[SEQ + HDIM + k] = cc;
  }
}

extern "C" void kernel_launch(void* const* d_in, const int* in_sizes, int n_in,
                              void* d_out, int out_size, void* d_ws, size_t ws_size,
                              hipStream_t stream) {
  const float* x     = (const float*)d_in[0];
  const float* w_ih  = (const float*)d_in[1];
  const float* w_hh  = (const float*)d_in[2];
  const float* b_ih  = (const float*)d_in[3];
  const float* b_hh  = (const float*)d_in[4];
  const float* w_out = (const float*)d_in[5];
  const float* b_out = (const float*)d_in[6];
  float* out = (float*)d_out;

  // ws layout: [0,16KB): hval[2][2048] float; [16KB,18KB): flags[2][256] uint
  float* hval = (float*)d_ws;
  unsigned* flags = (unsigned*)((char*)d_ws + 16 * 1024);

  lstm_init<<<8, 256, 0, stream>>>(hval, flags);
  lstm_persist<<<NWG, TPB, 0, stream>>>(x, w_ih, w_hh, b_ih, b_hh, w_out,
                                        b_out, out, hval, flags);
}